// Round 3
// baseline (256.371 us; speedup 1.0000x reference)
//
#include <hip/hip_runtime.h>
#include <hip/hip_bf16.h>
#include <stdint.h>

typedef __bf16 bf16_t;
typedef __bf16 bf16x8 __attribute__((ext_vector_type(8)));
typedef __bf16 bf16x4 __attribute__((ext_vector_type(4)));
typedef float f32x4 __attribute__((ext_vector_type(4)));

#define DEVI static __device__ __forceinline__

#define SBAR                                 \
  do {                                       \
    __builtin_amdgcn_sched_barrier(0);       \
    __builtin_amdgcn_s_barrier();            \
    __builtin_amdgcn_sched_barrier(0);       \
  } while (0)

// async global->LDS, 16B per lane. LDS dest = wave-uniform base + lane*16 (HW).
DEVI void gload_lds16(const void* g, void* lds) {
  __builtin_amdgcn_global_load_lds(
      (const __attribute__((address_space(1))) unsigned int*)g,
      (__attribute__((address_space(3))) unsigned int*)lds, 16, 0, 0);
}

// ---------------- f32 -> bf16 conversion (vectorized) ----------------
__global__ void cvt4(const float* __restrict__ in, bf16_t* __restrict__ out, int n4) {
  int i = blockIdx.x * blockDim.x + threadIdx.x;
  if (i < n4) {
    float4 v = ((const float4*)in)[i];
    bf16x4 o;
    o[0] = (bf16_t)v.x; o[1] = (bf16_t)v.y; o[2] = (bf16_t)v.z; o[3] = (bf16_t)v.w;
    ((bf16x4*)out)[i] = o;
  }
}

// ---------------- 256x256 8-phase GEMM: C[M,N] = A[M,K] @ B[N,K]^T + bias ----
// EPI: 0 = bf16 row-major out, 1 = f32 row-major out, 2 = QKV scatter
// 8 waves (2M x 4N), BK=64, double-buffered 128KB LDS, st-swizzle (row&7)<<4,
// raw s_barrier + counted vmcnt(4) at phases 4/8, setprio around MFMA clusters.
template <int EPI>
__global__ __launch_bounds__(512, 2) void gemm256(
    const bf16_t* __restrict__ A, const bf16_t* __restrict__ B,
    const float* __restrict__ bias, void* __restrict__ Cout,
    int M, int N, int K,
    bf16_t* __restrict__ qo, bf16_t* __restrict__ ko, bf16_t* __restrict__ vo) {
  __shared__ alignas(16) char lds[131072];  // A: [0,64K) B: [64K,128K)
  const int tid = threadIdx.x;
  const int wave = tid >> 6, lane = tid & 63;
  const int lr = lane & 15, lg = lane >> 4;
  const int wm = wave >> 2, wn = wave & 3;

  // XCD-aware swizzle (n_wg % 8 == 0 for all our launches)
  const int gx = gridDim.x;
  int lin = blockIdx.y * gx + blockIdx.x;
  const int cpx = (gx * gridDim.y) >> 3;
  lin = (lin & 7) * cpx + (lin >> 3);
  const int bm = (lin % gx) * 256, bn = (lin / gx) * 256;

  const int srow = tid >> 3;                  // 0..63 (row within 64-row block)
  const int schunk = (tid & 7) ^ (srow & 7);  // pre-swizzled global 16B chunk

  // stage one 64-row block (rb) of a K-tile t into buffer buf
  auto stA = [&](int buf, int t, int rb) {
    const bf16_t* g = A + (size_t)(bm + rb * 64 + srow) * K + t * 64 + schunk * 8;
    gload_lds16(g, lds + buf * 32768 + rb * 8192 + wave * 1024);
  };
  auto stB = [&](int buf, int t, int rb) {
    const bf16_t* g = B + (size_t)(bn + rb * 64 + srow) * K + t * 64 + schunk * 8;
    gload_lds16(g, lds + 65536 + buf * 32768 + rb * 8192 + wave * 1024);
  };
  // swizzled fragment reads (row&7 == lr&7 since frag rows are 16-aligned)
  auto ldA = [&](int buf, int mf, int kk) -> bf16x8 {
    const int row = wm * 128 + mf * 16 + lr;
    return *(const bf16x8*)(lds + buf * 32768 + row * 128 +
                            ((((kk << 2) + lg) ^ (lr & 7)) << 4));
  };
  auto ldB = [&](int buf, int nf, int kk) -> bf16x8 {
    const int row = wn * 64 + nf * 16 + lr;
    return *(const bf16x8*)(lds + 65536 + buf * 32768 + row * 128 +
                            ((((kk << 2) + lg) ^ (lr & 7)) << 4));
  };

  f32x4 acc[8][4];
#pragma unroll
  for (int m = 0; m < 8; m++)
#pragma unroll
    for (int n = 0; n < 4; n++) acc[m][n] = (f32x4){0.f, 0.f, 0.f, 0.f};

  auto mma16 = [&](bf16x8 (&ar)[4], bf16x8 (&bb)[4], int mb) {
    __builtin_amdgcn_s_setprio(1);
#pragma unroll
    for (int i = 0; i < 4; i++)
#pragma unroll
      for (int n = 0; n < 4; n++)
        acc[mb + i][n] =
            __builtin_amdgcn_mfma_f32_16x16x32_bf16(ar[i], bb[n], acc[mb + i][n], 0, 0, 0);
    __builtin_amdgcn_s_setprio(0);
  };

  const int nIter = K >> 7;  // pairs of K-tiles (K=1024 -> 8)

  // prologue: tile0 fully, tile1 A-q0 + B-b01 (12 items; newest 4 may lag)
  stA(0, 0, 0); stA(0, 0, 2); stA(0, 0, 1); stA(0, 0, 3);
  stB(0, 0, 0); stB(0, 0, 1); stB(0, 0, 2); stB(0, 0, 3);
  stA(1, 1, 0); stA(1, 1, 2); stB(1, 1, 0); stB(1, 1, 1);
  asm volatile("s_waitcnt vmcnt(4)" ::: "memory");
  SBAR;

  for (int j = 0; j < nIter; ++j) {
    const int t1 = 2 * j + 1, t2 = 2 * j + 2, t3 = 2 * j + 3;
    const bool more = (j + 1 < nIter);
    bf16x8 aq[4], bq[4], aq2[4];

    // ---- P1: buf0 A-q0 + B @kk0 ----
#pragma unroll
    for (int i = 0; i < 4; i++) aq[i] = ldA(0, i, 0);
#pragma unroll
    for (int n = 0; n < 4; n++) bq[n] = ldB(0, n, 0);
    stA(1, t1, 1); stA(1, t1, 3); stB(1, t1, 2); stB(1, t1, 3);
    SBAR;
    mma16(aq, bq, 0);
    SBAR;
    // ---- P2: buf0 A-q1 @kk0 ----
#pragma unroll
    for (int i = 0; i < 4; i++) aq2[i] = ldA(0, 4 + i, 0);
    SBAR;
    mma16(aq2, bq, 4);
    SBAR;
    // ---- P3: buf0 A-q0 + B @kk1 ----
#pragma unroll
    for (int i = 0; i < 4; i++) aq[i] = ldA(0, i, 1);
#pragma unroll
    for (int n = 0; n < 4; n++) bq[n] = ldB(0, n, 1);
    SBAR;
    mma16(aq, bq, 0);
    SBAR;
    // ---- P4: buf0 A-q1 @kk1 ; stage tile t2 q0+B01 ; checkpoint ----
#pragma unroll
    for (int i = 0; i < 4; i++) aq2[i] = ldA(0, 4 + i, 1);
    if (more) { stA(0, t2, 0); stA(0, t2, 2); stB(0, t2, 0); stB(0, t2, 1); }
    SBAR;
    mma16(aq2, bq, 4);
    if (more)
      asm volatile("s_waitcnt vmcnt(4)" ::: "memory");
    else
      asm volatile("s_waitcnt vmcnt(0)" ::: "memory");
    SBAR;
    // ---- P5: buf1 A-q0 + B @kk0 ; stage tile t2 q1+B23 ----
#pragma unroll
    for (int i = 0; i < 4; i++) aq[i] = ldA(1, i, 0);
#pragma unroll
    for (int n = 0; n < 4; n++) bq[n] = ldB(1, n, 0);
    if (more) { stA(0, t2, 1); stA(0, t2, 3); stB(0, t2, 2); stB(0, t2, 3); }
    SBAR;
    mma16(aq, bq, 0);
    SBAR;
    // ---- P6: buf1 A-q1 @kk0 ----
#pragma unroll
    for (int i = 0; i < 4; i++) aq2[i] = ldA(1, 4 + i, 0);
    SBAR;
    mma16(aq2, bq, 4);
    SBAR;
    // ---- P7: buf1 A-q0 + B @kk1 ----
#pragma unroll
    for (int i = 0; i < 4; i++) aq[i] = ldA(1, i, 1);
#pragma unroll
    for (int n = 0; n < 4; n++) bq[n] = ldB(1, n, 1);
    SBAR;
    mma16(aq, bq, 0);
    SBAR;
    // ---- P8: buf1 A-q1 @kk1 ; stage tile t3 q0+B01 ; checkpoint ----
#pragma unroll
    for (int i = 0; i < 4; i++) aq2[i] = ldA(1, 4 + i, 1);
    if (more) { stA(1, t3, 0); stA(1, t3, 2); stB(1, t3, 0); stB(1, t3, 1); }
    SBAR;
    mma16(aq2, bq, 4);
    if (more) asm volatile("s_waitcnt vmcnt(4)" ::: "memory");
    SBAR;
  }

  // Epilogue. C/D frag layout: row = 4*lg + i, col = lr.
#pragma unroll
  for (int nf = 0; nf < 4; nf++) {
    const int gc = bn + wn * 64 + nf * 16 + lr;
    const float bv = bias[gc];
#pragma unroll
    for (int mf = 0; mf < 8; mf++) {
#pragma unroll
      for (int i = 0; i < 4; i++) {
        const int gr = bm + wm * 128 + mf * 16 + lg * 4 + i;
        float v = acc[mf][nf][i] + bv;
        if (EPI == 0) {
          ((bf16_t*)Cout)[(size_t)gr * N + gc] = (bf16_t)v;
        } else if (EPI == 1) {
          ((float*)Cout)[(size_t)gr * N + gc] = v;
        } else {
          const int which = gc >> 10, e = gc & 1023, h = e >> 6, d = e & 63;
          const int b = gr >> 10, t = gr & 1023;
          const int bh = b * 16 + h;
          if (which == 0)
            qo[((size_t)bh * 1024 + t) * 64 + d] = (bf16_t)(v * 0.125f);
          else if (which == 1)
            ko[((size_t)bh * 1024 + t) * 64 + d] = (bf16_t)v;
          else
            vo[((size_t)bh * 64 + d) * 1024 + t] = (bf16_t)v;  // V transposed
        }
      }
    }
  }
}

// ---------------- causal flash attention (unchanged from round 2) ----------
__global__ __launch_bounds__(256) void attn_fwd(
    const bf16_t* __restrict__ Q, const bf16_t* __restrict__ K,
    const bf16_t* __restrict__ Vt, bf16_t* __restrict__ Out) {
  __shared__ alignas(16) bf16_t Ks[2][64][64];
  __shared__ alignas(16) bf16_t Vs[2][64][64];  // [d][kv]
  __shared__ alignas(16) bf16_t Ps[4][16][64];  // per-wave P[q][kv], swizzled
  const int tid = threadIdx.x, wave = tid >> 6, lane = tid & 63;
  const int lr = lane & 15, lg = lane >> 4;
  const int bx = blockIdx.x;  // 0..7 -> q-tiles {bx, 15-bx}
  const int bh = blockIdx.y;
  const int b = bh >> 4, h = bh & 15;
  const bf16_t* Qb = Q + (size_t)bh * 65536;
  const bf16_t* Kb = K + (size_t)bh * 65536;
  const bf16_t* Vb = Vt + (size_t)bh * 65536;

  const int srow = tid >> 3;
  const int schunk = (tid & 7) ^ (srow & 7);

  auto stage = [&](int bufn, int t) {
#pragma unroll
    for (int i = 0; i < 2; i++) {
      const bf16_t* g = Kb + (size_t)(t * 64 + srow + i * 32) * 64 + schunk * 8;
      gload_lds16(g, (char*)Ks[bufn] + i * 4096 + wave * 1024);
    }
#pragma unroll
    for (int i = 0; i < 2; i++) {
      const bf16_t* g = Vb + (size_t)(srow + i * 32) * 1024 + t * 64 + schunk * 8;
      gload_lds16(g, (char*)Vs[bufn] + i * 4096 + wave * 1024);
    }
  };
  auto ldtile = [&](const bf16_t (*tile)[64], int r, int kk) -> bf16x8 {
    return *(const bf16x8*)((const char*)tile + r * 128 +
                            ((((kk << 2) + lg) ^ (r & 7)) << 4));
  };
  char* psb = (char*)Ps + wave * 2048;

  int qt = bx;
  int qr = qt * 64 + wave * 16;
  bf16x8 qf[2];
#pragma unroll
  for (int kk = 0; kk < 2; kk++)
    qf[kk] = *(const bf16x8*)&Qb[(size_t)(qr + lr) * 64 + kk * 32 + lg * 8];

  f32x4 acc[4];
#pragma unroll
  for (int n = 0; n < 4; n++) acc[n] = (f32x4){0.f, 0.f, 0.f, 0.f};
  float m_s = -1e30f, l_s = 0.f;

  stage(0, 0);
  int buf = 0;
  for (int it = 0; it < 17; ++it) {
    const int t = (it <= bx) ? it : it - bx - 1;
    const bool lastOfPhase = (it == bx) || (it == 16);
    __syncthreads();
    if (it < 16) {
      const int tn = (it + 1 <= bx) ? it + 1 : it - bx;
      stage(buf ^ 1, tn);
    }

    f32x4 s[4];
#pragma unroll
    for (int n = 0; n < 4; n++) s[n] = (f32x4){0.f, 0.f, 0.f, 0.f};
#pragma unroll
    for (int kk = 0; kk < 2; kk++)
#pragma unroll
      for (int n = 0; n < 4; n++) {
        bf16x8 kf = ldtile(Ks[buf], n * 16 + lr, kk);
        s[n] = __builtin_amdgcn_mfma_f32_16x16x32_bf16(kf, qf[kk], s[n], 0, 0, 0);
      }

    if (lastOfPhase) {
      const int qa = qr + lr;
#pragma unroll
      for (int n = 0; n < 4; n++)
#pragma unroll
        for (int i = 0; i < 4; i++) {
          const int kv = t * 64 + n * 16 + 4 * lg + i;
          if (kv > qa) s[n][i] = -1e30f;
        }
    }

    float mx = s[0][0];
#pragma unroll
    for (int n = 0; n < 4; n++)
#pragma unroll
      for (int i = 0; i < 4; i++) mx = fmaxf(mx, s[n][i]);
    mx = fmaxf(mx, __shfl_xor(mx, 16, 64));
    mx = fmaxf(mx, __shfl_xor(mx, 32, 64));
    const float mnew = fmaxf(m_s, mx);
    const float alpha = __expf(m_s - mnew);
    m_s = mnew;
    float p[4][4];
    float rs = 0.f;
#pragma unroll
    for (int n = 0; n < 4; n++)
#pragma unroll
      for (int i = 0; i < 4; i++) {
        const float pv = __expf(s[n][i] - mnew);
        p[n][i] = pv;
        rs += pv;
      }
    rs += __shfl_xor(rs, 16, 64);
    rs += __shfl_xor(rs, 32, 64);
    l_s = l_s * alpha + rs;
#pragma unroll
    for (int i = 0; i < 4; i++) {
      const float ai = __shfl(alpha, 4 * lg + i, 64);
#pragma unroll
      for (int n = 0; n < 4; n++) acc[n][i] *= ai;
    }

#pragma unroll
    for (int n = 0; n < 4; n++) {
      bf16x4 pw;
#pragma unroll
      for (int i = 0; i < 4; i++) pw[i] = (bf16_t)p[n][i];
      *(bf16x4*)(psb + lr * 128 + ((((n << 1) + (lg >> 1)) ^ (lr & 7)) << 4) +
                 ((lg & 1) << 3)) = pw;
    }
#pragma unroll
    for (int kk = 0; kk < 2; kk++) {
      bf16x8 pa = *(const bf16x8*)(psb + lr * 128 +
                                   ((((kk << 2) + lg) ^ (lr & 7)) << 4));
#pragma unroll
      for (int n = 0; n < 4; n++) {
        bf16x8 vb = ldtile(Vs[buf], n * 16 + lr, kk);
        acc[n] = __builtin_amdgcn_mfma_f32_16x16x32_bf16(pa, vb, acc[n], 0, 0, 0);
      }
    }

    if (lastOfPhase) {
      const float invl = 1.f / l_s;
#pragma unroll
      for (int i = 0; i < 4; i++) {
        const float inv_i = __shfl(invl, 4 * lg + i, 64);
        const int qa = qr + 4 * lg + i;
#pragma unroll
        for (int n = 0; n < 4; n++)
          Out[((size_t)b * 1024 + qa) * 1024 + h * 64 + n * 16 + lr] =
              (bf16_t)(acc[n][i] * inv_i);
      }
      if (it == bx) {
        qt = 15 - bx;
        qr = qt * 64 + wave * 16;
#pragma unroll
        for (int kk = 0; kk < 2; kk++)
          qf[kk] = *(const bf16x8*)&Qb[(size_t)(qr + lr) * 64 + kk * 32 + lg * 8];
#pragma unroll
        for (int n = 0; n < 4; n++) acc[n] = (f32x4){0.f, 0.f, 0.f, 0.f};
        m_s = -1e30f;
        l_s = 0.f;
      }
    }
    buf ^= 1;
  }
}

// ---------------- launch ----------------
extern "C" void kernel_launch(void* const* d_in, const int* in_sizes, int n_in,
                              void* d_out, int out_size, void* d_ws, size_t ws_size,
                              hipStream_t stream) {
  const float* x = (const float*)d_in[0];
  const float* w_in = (const float*)d_in[1];
  const float* b_in = (const float*)d_in[2];
  const float* w_out = (const float*)d_in[3];
  const float* b_out = (const float*)d_in[4];
  const float* w_c = (const float*)d_in[5];
  const float* b_c = (const float*)d_in[6];
  float* out = (float*)d_out;

  const int M = 8192, E = 1024, N3 = 3072;
  char* ws = (char*)d_ws;
  size_t off = 0;
  auto alloc = [&](size_t bytes) {
    char* p = ws + off;
    off += (bytes + 255) & ~(size_t)255;
    return p;
  };
  bf16_t* xb = (bf16_t*)alloc((size_t)M * E * 2);
  bf16_t* wqb = (bf16_t*)alloc((size_t)N3 * E * 2);
  bf16_t* wob = (bf16_t*)alloc((size_t)E * E * 2);
  bf16_t* wcb = (bf16_t*)alloc((size_t)E * E * 2);
  bf16_t* Qs = (bf16_t*)alloc((size_t)M * E * 2);
  bf16_t* Kc = (bf16_t*)alloc((size_t)M * E * 2);
  bf16_t* Vt = (bf16_t*)alloc((size_t)M * E * 2);
  bf16_t* AO = (bf16_t*)alloc((size_t)M * E * 2);
  bf16_t* H1 = (bf16_t*)alloc((size_t)M * E * 2);

  cvt4<<<(M * E / 4 + 255) / 256, 256, 0, stream>>>(x, xb, M * E / 4);
  cvt4<<<(N3 * E / 4 + 255) / 256, 256, 0, stream>>>(w_in, wqb, N3 * E / 4);
  cvt4<<<(E * E / 4 + 255) / 256, 256, 0, stream>>>(w_out, wob, E * E / 4);
  cvt4<<<(E * E / 4 + 255) / 256, 256, 0, stream>>>(w_c, wcb, E * E / 4);

  gemm256<2><<<dim3(M / 256, N3 / 256), 512, 0, stream>>>(
      xb, wqb, b_in, nullptr, M, N3, E, Qs, Kc, Vt);
  attn_fwd<<<dim3(8, 128), 256, 0, stream>>>(Qs, Kc, Vt, AO);
  gemm256<0><<<dim3(M / 256, E / 256), 512, 0, stream>>>(
      AO, wob, b_out, H1, M, E, E, nullptr, nullptr, nullptr);
  gemm256<1><<<dim3(M / 256, E / 256), 512, 0, stream>>>(
      H1, wcb, b_c, out, M, E, E, nullptr, nullptr, nullptr);
}

// Round 4
// 204.501 us; speedup vs baseline: 1.2536x; 1.2536x over previous
//
#include <hip/hip_runtime.h>
#include <hip/hip_bf16.h>
#include <stdint.h>

typedef __bf16 bf16_t;
typedef __bf16 bf16x8 __attribute__((ext_vector_type(8)));
typedef __bf16 bf16x4 __attribute__((ext_vector_type(4)));
typedef float f32x4 __attribute__((ext_vector_type(4)));

#define DEVI static __device__ __forceinline__
#define VMCNT0 asm volatile("s_waitcnt vmcnt(0)" ::: "memory")

// async global->LDS, 16B per lane. LDS dest = wave-uniform base + lane*16 (HW).
DEVI void gload_lds16(const void* g, void* lds) {
  __builtin_amdgcn_global_load_lds(
      (const __attribute__((address_space(1))) unsigned int*)g,
      (__attribute__((address_space(3))) unsigned int*)lds, 16, 0, 0);
}

// ---------------- f32 -> bf16 conversion (vectorized) ----------------
__global__ void cvt4(const float* __restrict__ in, bf16_t* __restrict__ out, int n4) {
  int i = blockIdx.x * blockDim.x + threadIdx.x;
  if (i < n4) {
    float4 v = ((const float4*)in)[i];
    bf16x4 o;
    o[0] = (bf16_t)v.x; o[1] = (bf16_t)v.y; o[2] = (bf16_t)v.z; o[3] = (bf16_t)v.w;
    ((bf16x4*)out)[i] = o;
  }
}

// ---------------- 128x128 double-buffered GEMM: C = A @ B^T + bias --------
// EPI: 0 = bf16 row-major out, 1 = f32 row-major out, 2 = QKV scatter
// 4 waves (2x2), BK=64, 64KB LDS (2 blocks/CU), XOR-swizzle both sides,
// T3-minimum schedule: stage(next); compute(cur); vmcnt(0); barrier.
// bf16 epilogues roundtrip through LDS for fully-coalesced 16B stores.
template <int EPI>
__global__ __launch_bounds__(256, 2) void gemm_db(
    const bf16_t* __restrict__ A, const bf16_t* __restrict__ B,
    const float* __restrict__ bias, void* __restrict__ Cout,
    int M, int N, int K,
    bf16_t* __restrict__ qo, bf16_t* __restrict__ ko, bf16_t* __restrict__ vo) {
  __shared__ alignas(16) char lds[65536];  // A: [0,32K) dbuf, B: [32K,64K) dbuf
  const int tid = threadIdx.x;
  const int wave = tid >> 6, lane = tid & 63;
  const int lr = lane & 15, lg = lane >> 4;
  const int wr = wave >> 1, wc = wave & 1;

  // bijective XCD swizzle (all our grids have nwg % 8 == 0)
  const int gx = gridDim.x;
  const int nwg = gx * gridDim.y;
  int lin = blockIdx.y * gx + blockIdx.x;
  lin = (lin & 7) * (nwg >> 3) + (lin >> 3);
  const int bm = (lin % gx) * 128, bn = (lin / gx) * 128;

  const int srow = tid >> 3;                  // 0..31 (+32 per item)
  const int schunk = (tid & 7) ^ (srow & 7);  // pre-swizzled global 16B chunk

  auto stage = [&](int buf, int t) {
#pragma unroll
    for (int i = 0; i < 4; i++) {
      const bf16_t* ga = A + (size_t)(bm + srow + i * 32) * K + t * 64 + schunk * 8;
      gload_lds16(ga, lds + buf * 16384 + i * 4096 + wave * 1024);
      const bf16_t* gb = B + (size_t)(bn + srow + i * 32) * K + t * 64 + schunk * 8;
      gload_lds16(gb, lds + 32768 + buf * 16384 + i * 4096 + wave * 1024);
    }
  };
  auto ldA = [&](int buf, int mf, int kk) -> bf16x8 {
    const int row = wr * 64 + mf * 16 + lr;
    return *(const bf16x8*)(lds + buf * 16384 + row * 128 +
                            ((((kk << 2) + lg) ^ (row & 7)) << 4));
  };
  auto ldB = [&](int buf, int nf, int kk) -> bf16x8 {
    const int row = wc * 64 + nf * 16 + lr;
    return *(const bf16x8*)(lds + 32768 + buf * 16384 + row * 128 +
                            ((((kk << 2) + lg) ^ (row & 7)) << 4));
  };

  f32x4 acc[4][4];
#pragma unroll
  for (int m = 0; m < 4; m++)
#pragma unroll
    for (int n = 0; n < 4; n++) acc[m][n] = (f32x4){0.f, 0.f, 0.f, 0.f};

  const int nK = K >> 6;  // 16 for K=1024

  stage(0, 0);
  VMCNT0;
  __builtin_amdgcn_s_barrier();
  __builtin_amdgcn_sched_barrier(0);

  auto kstep = [&](int buf, int t, bool pre) {
    if (pre) stage(buf ^ 1, t + 1);  // prefetch: whole compute phase to land
    __builtin_amdgcn_sched_barrier(0);
#pragma unroll
    for (int kk = 0; kk < 2; kk++) {
      bf16x8 af[4], bfr[4];
#pragma unroll
      for (int m = 0; m < 4; m++) af[m] = ldA(buf, m, kk);
#pragma unroll
      for (int n = 0; n < 4; n++) bfr[n] = ldB(buf, n, kk);
#pragma unroll
      for (int m = 0; m < 4; m++)
#pragma unroll
        for (int n = 0; n < 4; n++)
          acc[m][n] = __builtin_amdgcn_mfma_f32_16x16x32_bf16(af[m], bfr[n], acc[m][n], 0, 0, 0);
    }
    __builtin_amdgcn_sched_barrier(0);
    VMCNT0;
    __builtin_amdgcn_s_barrier();
    __builtin_amdgcn_sched_barrier(0);
  };
  for (int t = 0; t < nK; t += 2) {
    kstep(0, t, true);
    kstep(1, t + 1, t + 2 < nK);
  }

  // ---------------- epilogue ----------------
  if (EPI == 1) {
    // f32 direct stores (64B per lg-group, acceptable for f32)
#pragma unroll
    for (int nf = 0; nf < 4; nf++) {
      const int gc = bn + wc * 64 + nf * 16 + lr;
      const float bv = bias[gc];
#pragma unroll
      for (int mf = 0; mf < 4; mf++)
#pragma unroll
        for (int i = 0; i < 4; i++) {
          const int gr = bm + wr * 64 + mf * 16 + lg * 4 + i;
          ((float*)Cout)[(size_t)gr * N + gc] = acc[mf][nf][i] + bv;
        }
    }
    return;
  }
  // bf16 paths: LDS roundtrip for coalesced stores. [128][132] bf16 = 33.8KB.
  bf16_t(*ep)[132] = (bf16_t(*)[132])lds;
  const bool vblk = (EPI == 2) && (bn >= 2048);  // V-block: store transposed
  const bool qblk = (EPI == 2) && (bn < 1024);
#pragma unroll
  for (int nf = 0; nf < 4; nf++) {
    const int col = wc * 64 + nf * 16 + lr;
    const float bv = bias[bn + col];
#pragma unroll
    for (int mf = 0; mf < 4; mf++)
#pragma unroll
      for (int i = 0; i < 4; i++) {
        const int row = wr * 64 + mf * 16 + lg * 4 + i;
        float v = acc[mf][nf][i] + bv;
        if (qblk) v *= 0.125f;  // fold 1/sqrt(64) into Q
        if (vblk)
          ep[col][row] = (bf16_t)v;  // transposed: LDS row = output d
        else
          ep[row][col] = (bf16_t)v;
      }
  }
  __syncthreads();
#pragma unroll
  for (int rr = 0; rr < 8; rr++) {
    const int row = rr * 16 + (tid >> 4);
    const int c0 = (tid & 15) * 8;
    bf16x8 val = *(const bf16x8*)&ep[row][c0];
    if (EPI == 0) {
      *(bf16x8*)&((bf16_t*)Cout)[(size_t)(bm + row) * N + bn + c0] = val;
    } else if (!vblk) {
      // Q/K: LDS row -> (b,t); col -> (which,h,d). c0..c0+7 within one head.
      const int gr = bm + row, b = gr >> 10, t = gr & 1023;
      const int e = bn + c0;
      const int which = e >> 10, eh = e & 1023, h = eh >> 6, d = eh & 63;
      bf16_t* dst = (which == 0 ? qo : ko) + ((size_t)(b * 16 + h) * 1024 + t) * 64 + d;
      *(bf16x8*)dst = val;
    } else {
      // V: LDS row = output col (d-dim); LDS col = t
      const int e = bn + row - 2048, h = e >> 6, d = e & 63;
      const int gt = bm + c0, b = gt >> 10, t = gt & 1023;
      bf16_t* dst = vo + ((size_t)(b * 16 + h) * 64 + d) * 1024 + t;
      *(bf16x8*)dst = val;
    }
  }
}

// ---------------- causal flash attention (unchanged from round 2) ----------
__global__ __launch_bounds__(256) void attn_fwd(
    const bf16_t* __restrict__ Q, const bf16_t* __restrict__ K,
    const bf16_t* __restrict__ Vt, bf16_t* __restrict__ Out) {
  __shared__ alignas(16) bf16_t Ks[2][64][64];
  __shared__ alignas(16) bf16_t Vs[2][64][64];  // [d][kv]
  __shared__ alignas(16) bf16_t Ps[4][16][64];  // per-wave P[q][kv], swizzled
  const int tid = threadIdx.x, wave = tid >> 6, lane = tid & 63;
  const int lr = lane & 15, lg = lane >> 4;
  const int bx = blockIdx.x;  // 0..7 -> q-tiles {bx, 15-bx}
  const int bh = blockIdx.y;
  const int b = bh >> 4, h = bh & 15;
  const bf16_t* Qb = Q + (size_t)bh * 65536;
  const bf16_t* Kb = K + (size_t)bh * 65536;
  const bf16_t* Vb = Vt + (size_t)bh * 65536;

  const int srow = tid >> 3;
  const int schunk = (tid & 7) ^ (srow & 7);

  auto stage = [&](int bufn, int t) {
#pragma unroll
    for (int i = 0; i < 2; i++) {
      const bf16_t* g = Kb + (size_t)(t * 64 + srow + i * 32) * 64 + schunk * 8;
      gload_lds16(g, (char*)Ks[bufn] + i * 4096 + wave * 1024);
    }
#pragma unroll
    for (int i = 0; i < 2; i++) {
      const bf16_t* g = Vb + (size_t)(srow + i * 32) * 1024 + t * 64 + schunk * 8;
      gload_lds16(g, (char*)Vs[bufn] + i * 4096 + wave * 1024);
    }
  };
  auto ldtile = [&](const bf16_t (*tile)[64], int r, int kk) -> bf16x8 {
    return *(const bf16x8*)((const char*)tile + r * 128 +
                            ((((kk << 2) + lg) ^ (r & 7)) << 4));
  };
  char* psb = (char*)Ps + wave * 2048;

  int qt = bx;
  int qr = qt * 64 + wave * 16;
  bf16x8 qf[2];
#pragma unroll
  for (int kk = 0; kk < 2; kk++)
    qf[kk] = *(const bf16x8*)&Qb[(size_t)(qr + lr) * 64 + kk * 32 + lg * 8];

  f32x4 acc[4];
#pragma unroll
  for (int n = 0; n < 4; n++) acc[n] = (f32x4){0.f, 0.f, 0.f, 0.f};
  float m_s = -1e30f, l_s = 0.f;

  stage(0, 0);
  int buf = 0;
  for (int it = 0; it < 17; ++it) {
    const int t = (it <= bx) ? it : it - bx - 1;
    const bool lastOfPhase = (it == bx) || (it == 16);
    __syncthreads();
    if (it < 16) {
      const int tn = (it + 1 <= bx) ? it + 1 : it - bx;
      stage(buf ^ 1, tn);
    }

    f32x4 s[4];
#pragma unroll
    for (int n = 0; n < 4; n++) s[n] = (f32x4){0.f, 0.f, 0.f, 0.f};
#pragma unroll
    for (int kk = 0; kk < 2; kk++)
#pragma unroll
      for (int n = 0; n < 4; n++) {
        bf16x8 kf = ldtile(Ks[buf], n * 16 + lr, kk);
        s[n] = __builtin_amdgcn_mfma_f32_16x16x32_bf16(kf, qf[kk], s[n], 0, 0, 0);
      }

    if (lastOfPhase) {
      const int qa = qr + lr;
#pragma unroll
      for (int n = 0; n < 4; n++)
#pragma unroll
        for (int i = 0; i < 4; i++) {
          const int kv = t * 64 + n * 16 + 4 * lg + i;
          if (kv > qa) s[n][i] = -1e30f;
        }
    }

    float mx = s[0][0];
#pragma unroll
    for (int n = 0; n < 4; n++)
#pragma unroll
      for (int i = 0; i < 4; i++) mx = fmaxf(mx, s[n][i]);
    mx = fmaxf(mx, __shfl_xor(mx, 16, 64));
    mx = fmaxf(mx, __shfl_xor(mx, 32, 64));
    const float mnew = fmaxf(m_s, mx);
    const float alpha = __expf(m_s - mnew);
    m_s = mnew;
    float p[4][4];
    float rs = 0.f;
#pragma unroll
    for (int n = 0; n < 4; n++)
#pragma unroll
      for (int i = 0; i < 4; i++) {
        const float pv = __expf(s[n][i] - mnew);
        p[n][i] = pv;
        rs += pv;
      }
    rs += __shfl_xor(rs, 16, 64);
    rs += __shfl_xor(rs, 32, 64);
    l_s = l_s * alpha + rs;
#pragma unroll
    for (int i = 0; i < 4; i++) {
      const float ai = __shfl(alpha, 4 * lg + i, 64);
#pragma unroll
      for (int n = 0; n < 4; n++) acc[n][i] *= ai;
    }

#pragma unroll
    for (int n = 0; n < 4; n++) {
      bf16x4 pw;
#pragma unroll
      for (int i = 0; i < 4; i++) pw[i] = (bf16_t)p[n][i];
      *(bf16x4*)(psb + lr * 128 + ((((n << 1) + (lg >> 1)) ^ (lr & 7)) << 4) +
                 ((lg & 1) << 3)) = pw;
    }
#pragma unroll
    for (int kk = 0; kk < 2; kk++) {
      bf16x8 pa = *(const bf16x8*)(psb + lr * 128 +
                                   ((((kk << 2) + lg) ^ (lr & 7)) << 4));
#pragma unroll
      for (int n = 0; n < 4; n++) {
        bf16x8 vb = ldtile(Vs[buf], n * 16 + lr, kk);
        acc[n] = __builtin_amdgcn_mfma_f32_16x16x32_bf16(pa, vb, acc[n], 0, 0, 0);
      }
    }

    if (lastOfPhase) {
      const float invl = 1.f / l_s;
#pragma unroll
      for (int i = 0; i < 4; i++) {
        const float inv_i = __shfl(invl, 4 * lg + i, 64);
        const int qa = qr + 4 * lg + i;
#pragma unroll
        for (int n = 0; n < 4; n++)
          Out[((size_t)b * 1024 + qa) * 1024 + h * 64 + n * 16 + lr] =
              (bf16_t)(acc[n][i] * inv_i);
      }
      if (it == bx) {
        qt = 15 - bx;
        qr = qt * 64 + wave * 16;
#pragma unroll
        for (int kk = 0; kk < 2; kk++)
          qf[kk] = *(const bf16x8*)&Qb[(size_t)(qr + lr) * 64 + kk * 32 + lg * 8];
#pragma unroll
        for (int n = 0; n < 4; n++) acc[n] = (f32x4){0.f, 0.f, 0.f, 0.f};
        m_s = -1e30f;
        l_s = 0.f;
      }
    }
    buf ^= 1;
  }
}

// ---------------- launch ----------------
extern "C" void kernel_launch(void* const* d_in, const int* in_sizes, int n_in,
                              void* d_out, int out_size, void* d_ws, size_t ws_size,
                              hipStream_t stream) {
  const float* x = (const float*)d_in[0];
  const float* w_in = (const float*)d_in[1];
  const float* b_in = (const float*)d_in[2];
  const float* w_out = (const float*)d_in[3];
  const float* b_out = (const float*)d_in[4];
  const float* w_c = (const float*)d_in[5];
  const float* b_c = (const float*)d_in[6];
  float* out = (float*)d_out;

  const int M = 8192, E = 1024, N3 = 3072;
  char* ws = (char*)d_ws;
  size_t off = 0;
  auto alloc = [&](size_t bytes) {
    char* p = ws + off;
    off += (bytes + 255) & ~(size_t)255;
    return p;
  };
  bf16_t* xb = (bf16_t*)alloc((size_t)M * E * 2);
  bf16_t* wqb = (bf16_t*)alloc((size_t)N3 * E * 2);
  bf16_t* wob = (bf16_t*)alloc((size_t)E * E * 2);
  bf16_t* wcb = (bf16_t*)alloc((size_t)E * E * 2);
  bf16_t* Qs = (bf16_t*)alloc((size_t)M * E * 2);
  bf16_t* Kc = (bf16_t*)alloc((size_t)M * E * 2);
  bf16_t* Vt = (bf16_t*)alloc((size_t)M * E * 2);
  bf16_t* AO = (bf16_t*)alloc((size_t)M * E * 2);
  bf16_t* H1 = (bf16_t*)alloc((size_t)M * E * 2);

  cvt4<<<(M * E / 4 + 255) / 256, 256, 0, stream>>>(x, xb, M * E / 4);
  cvt4<<<(N3 * E / 4 + 255) / 256, 256, 0, stream>>>(w_in, wqb, N3 * E / 4);
  cvt4<<<(E * E / 4 + 255) / 256, 256, 0, stream>>>(w_out, wob, E * E / 4);
  cvt4<<<(E * E / 4 + 255) / 256, 256, 0, stream>>>(w_c, wcb, E * E / 4);

  gemm_db<2><<<dim3(M / 128, N3 / 128), 256, 0, stream>>>(
      xb, wqb, b_in, nullptr, M, N3, E, Qs, Kc, Vt);
  attn_fwd<<<dim3(8, 128), 256, 0, stream>>>(Qs, Kc, Vt, AO);
  gemm_db<0><<<dim3(M / 128, E / 128), 256, 0, stream>>>(
      AO, wob, b_out, H1, M, E, E, nullptr, nullptr, nullptr);
  gemm_db<1><<<dim3(M / 128, E / 128), 256, 0, stream>>>(
      H1, wcb, b_c, out, M, E, E, nullptr, nullptr, nullptr);
}

// Round 5
// 185.417 us; speedup vs baseline: 1.3827x; 1.1029x over previous
//
#include <hip/hip_runtime.h>
#include <hip/hip_bf16.h>
#include <stdint.h>

typedef __bf16 bf16_t;
typedef __bf16 bf16x8 __attribute__((ext_vector_type(8)));
typedef __bf16 bf16x4 __attribute__((ext_vector_type(4)));
typedef float f32x4 __attribute__((ext_vector_type(4)));

#define DEVI static __device__ __forceinline__
#define VMCNT0 asm volatile("s_waitcnt vmcnt(0)" ::: "memory")

// async global->LDS, 16B per lane. LDS dest = wave-uniform base + lane*16 (HW).
DEVI void gload_lds16(const void* g, void* lds) {
  __builtin_amdgcn_global_load_lds(
      (const __attribute__((address_space(1))) unsigned int*)g,
      (__attribute__((address_space(3))) unsigned int*)lds, 16, 0, 0);
}

// ---------------- f32 -> bf16 conversion (vectorized) ----------------
__global__ void cvt4(const float* __restrict__ in, bf16_t* __restrict__ out, int n4) {
  int i = blockIdx.x * blockDim.x + threadIdx.x;
  if (i < n4) {
    float4 v = ((const float4*)in)[i];
    bf16x4 o;
    o[0] = (bf16_t)v.x; o[1] = (bf16_t)v.y; o[2] = (bf16_t)v.z; o[3] = (bf16_t)v.w;
    ((bf16x4*)out)[i] = o;
  }
}

// ---------------- f32 -> bf16 TRANSPOSING cvt (32x32 LDS tiles) ------------
// out[c][r] = (bf16) in[r][c], square n x n.
__global__ void cvtT(const float* __restrict__ in, bf16_t* __restrict__ out, int n) {
  __shared__ float ls[32][36];
  const int tid = threadIdx.x;
  const int R0 = blockIdx.y * 32, C0 = blockIdx.x * 32;
  {
    const int r = tid >> 3, c4 = (tid & 7) * 4;
    float4 v = *(const float4*)&in[(size_t)(R0 + r) * n + C0 + c4];
    ls[r][c4 + 0] = v.x; ls[r][c4 + 1] = v.y; ls[r][c4 + 2] = v.z; ls[r][c4 + 3] = v.w;
  }
  __syncthreads();
  {
    const int c = tid >> 3, r4 = (tid & 7) * 4;
    bf16x4 o;
#pragma unroll
    for (int j = 0; j < 4; j++) o[j] = (bf16_t)ls[r4 + j][c];
    *(bf16x4*)&out[(size_t)(C0 + c) * n + R0 + r4] = o;
  }
}

// ---------------- fused bias: b2[n] = bc[n] + sum_k bo[k]*Wc[n][k] ---------
__global__ void bias2k(const float* __restrict__ bo, const float* __restrict__ wc,
                       const float* __restrict__ bc, float* __restrict__ b2) {
  const int wid = (blockIdx.x * blockDim.x + threadIdx.x) >> 6;  // 0..1023
  const int lane = threadIdx.x & 63;
  float s = 0.f;
  for (int k = lane; k < 1024; k += 64) s += bo[k] * wc[(size_t)wid * 1024 + k];
#pragma unroll
  for (int o = 32; o; o >>= 1) s += __shfl_xor(s, o, 64);
  if (lane == 0) b2[wid] = s + bc[wid];
}

// ---------------- 128x128 double-buffered GEMM: C = A @ B^T + bias --------
// EPI: 0 = bf16 row-major out, 1 = f32 row-major out, 2 = QKV scatter
// L2-locality block order: each XCD owns an 8-bm-tile A-panel chunk (2MB,
// L2-resident) and walks bn; groups of 8 consecutive blocks share a B-panel.
template <int EPI>
__global__ __launch_bounds__(256, 2) void gemm_db(
    const bf16_t* __restrict__ A, const bf16_t* __restrict__ B,
    const float* __restrict__ bias, void* __restrict__ Cout,
    int M, int N, int K,
    bf16_t* __restrict__ qo, bf16_t* __restrict__ ko, bf16_t* __restrict__ vo) {
  __shared__ alignas(16) char lds[65536];  // A: [0,32K) dbuf, B: [32K,64K) dbuf
  const int tid = threadIdx.x;
  const int wave = tid >> 6, lane = tid & 63;
  const int lr = lane & 15, lg = lane >> 4;
  const int wr = wave >> 1, wc = wave & 1;

  // XCD-chunked mapping (requires gridDim.x % 8 == 0 or gridDim.x==8):
  // xcd owns bm tiles [xcd*bmx, (xcd+1)*bmx); consecutive idx walks bm within
  // the chunk (B-panel shared), every bmx advances bn (A-panel L2-resident).
  const int gx = gridDim.x;
  const int lin = blockIdx.y * gx + blockIdx.x;
  const int xcd = lin & 7, idx = lin >> 3;
  const int bmx = gx >> 3;  // bm tiles per xcd (gx=64 -> 8; gx=8 -> 1)
  const int bm = (xcd * bmx + (bmx > 1 ? idx % bmx : 0)) * 128;
  const int bn = (bmx > 1 ? idx / bmx : idx) * 128;

  const int srow = tid >> 3;                  // 0..31 (+32 per item)
  const int schunk = (tid & 7) ^ (srow & 7);  // pre-swizzled global 16B chunk

  auto stage = [&](int buf, int t) {
#pragma unroll
    for (int i = 0; i < 4; i++) {
      const bf16_t* ga = A + (size_t)(bm + srow + i * 32) * K + t * 64 + schunk * 8;
      gload_lds16(ga, lds + buf * 16384 + i * 4096 + wave * 1024);
      const bf16_t* gb = B + (size_t)(bn + srow + i * 32) * K + t * 64 + schunk * 8;
      gload_lds16(gb, lds + 32768 + buf * 16384 + i * 4096 + wave * 1024);
    }
  };
  auto ldA = [&](int buf, int mf, int kk) -> bf16x8 {
    const int row = wr * 64 + mf * 16 + lr;
    return *(const bf16x8*)(lds + buf * 16384 + row * 128 +
                            ((((kk << 2) + lg) ^ (row & 7)) << 4));
  };
  auto ldB = [&](int buf, int nf, int kk) -> bf16x8 {
    const int row = wc * 64 + nf * 16 + lr;
    return *(const bf16x8*)(lds + 32768 + buf * 16384 + row * 128 +
                            ((((kk << 2) + lg) ^ (row & 7)) << 4));
  };

  f32x4 acc[4][4];
#pragma unroll
  for (int m = 0; m < 4; m++)
#pragma unroll
    for (int n = 0; n < 4; n++) acc[m][n] = (f32x4){0.f, 0.f, 0.f, 0.f};

  const int nK = K >> 6;  // 16 for K=1024

  stage(0, 0);
  VMCNT0;
  __builtin_amdgcn_s_barrier();
  __builtin_amdgcn_sched_barrier(0);

  auto kstep = [&](int buf, int t, bool pre) {
    if (pre) stage(buf ^ 1, t + 1);  // prefetch: whole compute phase to land
    __builtin_amdgcn_sched_barrier(0);
#pragma unroll
    for (int kk = 0; kk < 2; kk++) {
      bf16x8 af[4], bfr[4];
#pragma unroll
      for (int m = 0; m < 4; m++) af[m] = ldA(buf, m, kk);
#pragma unroll
      for (int n = 0; n < 4; n++) bfr[n] = ldB(buf, n, kk);
#pragma unroll
      for (int m = 0; m < 4; m++)
#pragma unroll
        for (int n = 0; n < 4; n++)
          acc[m][n] = __builtin_amdgcn_mfma_f32_16x16x32_bf16(af[m], bfr[n], acc[m][n], 0, 0, 0);
    }
    __builtin_amdgcn_sched_barrier(0);
    VMCNT0;
    __builtin_amdgcn_s_barrier();
    __builtin_amdgcn_sched_barrier(0);
  };
  for (int t = 0; t < nK; t += 2) {
    kstep(0, t, true);
    kstep(1, t + 1, t + 2 < nK);
  }

  // ---------------- epilogue ----------------
  if (EPI == 1) {
#pragma unroll
    for (int nf = 0; nf < 4; nf++) {
      const int gc = bn + wc * 64 + nf * 16 + lr;
      const float bv = bias[gc];
#pragma unroll
      for (int mf = 0; mf < 4; mf++)
#pragma unroll
        for (int i = 0; i < 4; i++) {
          const int gr = bm + wr * 64 + mf * 16 + lg * 4 + i;
          ((float*)Cout)[(size_t)gr * N + gc] = acc[mf][nf][i] + bv;
        }
    }
    return;
  }
  // bf16 paths: LDS roundtrip for coalesced stores. [128][132] bf16 = 33.8KB.
  bf16_t(*ep)[132] = (bf16_t(*)[132])lds;
  const bool vblk = (EPI == 2) && (bn >= 2048);  // V-block: store transposed
  const bool qblk = (EPI == 2) && (bn < 1024);
#pragma unroll
  for (int nf = 0; nf < 4; nf++) {
    const int col = wc * 64 + nf * 16 + lr;
    const float bv = bias ? bias[bn + col] : 0.f;
#pragma unroll
    for (int mf = 0; mf < 4; mf++)
#pragma unroll
      for (int i = 0; i < 4; i++) {
        const int row = wr * 64 + mf * 16 + lg * 4 + i;
        float v = acc[mf][nf][i] + bv;
        if (qblk) v *= 0.125f;  // fold 1/sqrt(64) into Q
        if (vblk)
          ep[col][row] = (bf16_t)v;  // transposed: LDS row = output d
        else
          ep[row][col] = (bf16_t)v;
      }
  }
  __syncthreads();
#pragma unroll
  for (int rr = 0; rr < 8; rr++) {
    const int row = rr * 16 + (tid >> 4);
    const int c0 = (tid & 15) * 8;
    bf16x8 val = *(const bf16x8*)&ep[row][c0];
    if (EPI == 0) {
      *(bf16x8*)&((bf16_t*)Cout)[(size_t)(bm + row) * N + bn + c0] = val;
    } else if (!vblk) {
      const int gr = bm + row, b = gr >> 10, t = gr & 1023;
      const int e = bn + c0;
      const int which = e >> 10, eh = e & 1023, h = eh >> 6, d = eh & 63;
      bf16_t* dst = (which == 0 ? qo : ko) + ((size_t)(b * 16 + h) * 1024 + t) * 64 + d;
      *(bf16x8*)dst = val;
    } else {
      const int e = bn + row - 2048, h = e >> 6, d = e & 63;
      const int gt = bm + c0, b = gt >> 10, t = gt & 1023;
      bf16_t* dst = vo + ((size_t)(b * 16 + h) * 64 + d) * 1024 + t;
      *(bf16x8*)dst = val;
    }
  }
}

// ---------------- causal flash attention (unchanged) ----------------------
__global__ __launch_bounds__(256) void attn_fwd(
    const bf16_t* __restrict__ Q, const bf16_t* __restrict__ K,
    const bf16_t* __restrict__ Vt, bf16_t* __restrict__ Out) {
  __shared__ alignas(16) bf16_t Ks[2][64][64];
  __shared__ alignas(16) bf16_t Vs[2][64][64];  // [d][kv]
  __shared__ alignas(16) bf16_t Ps[4][16][64];  // per-wave P[q][kv], swizzled
  const int tid = threadIdx.x, wave = tid >> 6, lane = tid & 63;
  const int lr = lane & 15, lg = lane >> 4;
  const int bx = blockIdx.x;  // 0..7 -> q-tiles {bx, 15-bx}
  const int bh = blockIdx.y;
  const int b = bh >> 4, h = bh & 15;
  const bf16_t* Qb = Q + (size_t)bh * 65536;
  const bf16_t* Kb = K + (size_t)bh * 65536;
  const bf16_t* Vb = Vt + (size_t)bh * 65536;

  const int srow = tid >> 3;
  const int schunk = (tid & 7) ^ (srow & 7);

  auto stage = [&](int bufn, int t) {
#pragma unroll
    for (int i = 0; i < 2; i++) {
      const bf16_t* g = Kb + (size_t)(t * 64 + srow + i * 32) * 64 + schunk * 8;
      gload_lds16(g, (char*)Ks[bufn] + i * 4096 + wave * 1024);
    }
#pragma unroll
    for (int i = 0; i < 2; i++) {
      const bf16_t* g = Vb + (size_t)(srow + i * 32) * 1024 + t * 64 + schunk * 8;
      gload_lds16(g, (char*)Vs[bufn] + i * 4096 + wave * 1024);
    }
  };
  auto ldtile = [&](const bf16_t (*tile)[64], int r, int kk) -> bf16x8 {
    return *(const bf16x8*)((const char*)tile + r * 128 +
                            ((((kk << 2) + lg) ^ (r & 7)) << 4));
  };
  char* psb = (char*)Ps + wave * 2048;

  int qt = bx;
  int qr = qt * 64 + wave * 16;
  bf16x8 qf[2];
#pragma unroll
  for (int kk = 0; kk < 2; kk++)
    qf[kk] = *(const bf16x8*)&Qb[(size_t)(qr + lr) * 64 + kk * 32 + lg * 8];

  f32x4 acc[4];
#pragma unroll
  for (int n = 0; n < 4; n++) acc[n] = (f32x4){0.f, 0.f, 0.f, 0.f};
  float m_s = -1e30f, l_s = 0.f;

  stage(0, 0);
  int buf = 0;
  for (int it = 0; it < 17; ++it) {
    const int t = (it <= bx) ? it : it - bx - 1;
    const bool lastOfPhase = (it == bx) || (it == 16);
    __syncthreads();
    if (it < 16) {
      const int tn = (it + 1 <= bx) ? it + 1 : it - bx;
      stage(buf ^ 1, tn);
    }

    f32x4 s[4];
#pragma unroll
    for (int n = 0; n < 4; n++) s[n] = (f32x4){0.f, 0.f, 0.f, 0.f};
#pragma unroll
    for (int kk = 0; kk < 2; kk++)
#pragma unroll
      for (int n = 0; n < 4; n++) {
        bf16x8 kf = ldtile(Ks[buf], n * 16 + lr, kk);
        s[n] = __builtin_amdgcn_mfma_f32_16x16x32_bf16(kf, qf[kk], s[n], 0, 0, 0);
      }

    if (lastOfPhase) {
      const int qa = qr + lr;
#pragma unroll
      for (int n = 0; n < 4; n++)
#pragma unroll
        for (int i = 0; i < 4; i++) {
          const int kv = t * 64 + n * 16 + 4 * lg + i;
          if (kv > qa) s[n][i] = -1e30f;
        }
    }

    float mx = s[0][0];
#pragma unroll
    for (int n = 0; n < 4; n++)
#pragma unroll
      for (int i = 0; i < 4; i++) mx = fmaxf(mx, s[n][i]);
    mx = fmaxf(mx, __shfl_xor(mx, 16, 64));
    mx = fmaxf(mx, __shfl_xor(mx, 32, 64));
    const float mnew = fmaxf(m_s, mx);
    const float alpha = __expf(m_s - mnew);
    m_s = mnew;
    float p[4][4];
    float rs = 0.f;
#pragma unroll
    for (int n = 0; n < 4; n++)
#pragma unroll
      for (int i = 0; i < 4; i++) {
        const float pv = __expf(s[n][i] - mnew);
        p[n][i] = pv;
        rs += pv;
      }
    rs += __shfl_xor(rs, 16, 64);
    rs += __shfl_xor(rs, 32, 64);
    l_s = l_s * alpha + rs;
#pragma unroll
    for (int i = 0; i < 4; i++) {
      const float ai = __shfl(alpha, 4 * lg + i, 64);
#pragma unroll
      for (int n = 0; n < 4; n++) acc[n][i] *= ai;
    }

#pragma unroll
    for (int n = 0; n < 4; n++) {
      bf16x4 pw;
#pragma unroll
      for (int i = 0; i < 4; i++) pw[i] = (bf16_t)p[n][i];
      *(bf16x4*)(psb + lr * 128 + ((((n << 1) + (lg >> 1)) ^ (lr & 7)) << 4) +
                 ((lg & 1) << 3)) = pw;
    }
#pragma unroll
    for (int kk = 0; kk < 2; kk++) {
      bf16x8 pa = *(const bf16x8*)(psb + lr * 128 +
                                   ((((kk << 2) + lg) ^ (lr & 7)) << 4));
#pragma unroll
      for (int n = 0; n < 4; n++) {
        bf16x8 vb = ldtile(Vs[buf], n * 16 + lr, kk);
        acc[n] = __builtin_amdgcn_mfma_f32_16x16x32_bf16(pa, vb, acc[n], 0, 0, 0);
      }
    }

    if (lastOfPhase) {
      const float invl = 1.f / l_s;
#pragma unroll
      for (int i = 0; i < 4; i++) {
        const float inv_i = __shfl(invl, 4 * lg + i, 64);
        const int qa = qr + 4 * lg + i;
#pragma unroll
        for (int n = 0; n < 4; n++)
          Out[((size_t)b * 1024 + qa) * 1024 + h * 64 + n * 16 + lr] =
              (bf16_t)(acc[n][i] * inv_i);
      }
      if (it == bx) {
        qt = 15 - bx;
        qr = qt * 64 + wave * 16;
#pragma unroll
        for (int kk = 0; kk < 2; kk++)
          qf[kk] = *(const bf16x8*)&Qb[(size_t)(qr + lr) * 64 + kk * 32 + lg * 8];
#pragma unroll
        for (int n = 0; n < 4; n++) acc[n] = (f32x4){0.f, 0.f, 0.f, 0.f};
        m_s = -1e30f;
        l_s = 0.f;
      }
    }
    buf ^= 1;
  }
}

// ---------------- launch ----------------
extern "C" void kernel_launch(void* const* d_in, const int* in_sizes, int n_in,
                              void* d_out, int out_size, void* d_ws, size_t ws_size,
                              hipStream_t stream) {
  const float* x = (const float*)d_in[0];
  const float* w_in = (const float*)d_in[1];
  const float* b_in = (const float*)d_in[2];
  const float* w_out = (const float*)d_in[3];
  const float* b_out = (const float*)d_in[4];
  const float* w_c = (const float*)d_in[5];
  const float* b_c = (const float*)d_in[6];
  float* out = (float*)d_out;

  const int M = 8192, E = 1024, N3 = 3072;
  char* ws = (char*)d_ws;
  size_t off = 0;
  auto alloc = [&](size_t bytes) {
    char* p = ws + off;
    off += (bytes + 255) & ~(size_t)255;
    return p;
  };
  bf16_t* xb = (bf16_t*)alloc((size_t)M * E * 2);
  bf16_t* wqb = (bf16_t*)alloc((size_t)N3 * E * 2);
  bf16_t* wcb = (bf16_t*)alloc((size_t)E * E * 2);
  bf16_t* wotb = (bf16_t*)alloc((size_t)E * E * 2);    // w_out TRANSPOSED bf16
  bf16_t* wcombb = (bf16_t*)alloc((size_t)E * E * 2);  // Wc @ Wo, bf16
  float* b2 = (float*)alloc((size_t)E * 4);            // bo @ Wc^T + bc
  bf16_t* Qs = (bf16_t*)alloc((size_t)M * E * 2);
  bf16_t* Kc = (bf16_t*)alloc((size_t)M * E * 2);
  bf16_t* Vt = (bf16_t*)alloc((size_t)M * E * 2);
  bf16_t* AO = (bf16_t*)alloc((size_t)M * E * 2);

  cvt4<<<(M * E / 4 + 255) / 256, 256, 0, stream>>>(x, xb, M * E / 4);
  cvt4<<<(N3 * E / 4 + 255) / 256, 256, 0, stream>>>(w_in, wqb, N3 * E / 4);
  cvt4<<<(E * E / 4 + 255) / 256, 256, 0, stream>>>(w_c, wcb, E * E / 4);
  cvtT<<<dim3(32, 32), 256, 0, stream>>>(w_out, wotb, E);
  bias2k<<<256, 256, 0, stream>>>(b_out, w_c, b_c, b2);

  // Wcomb = Wc @ Wo  (A = Wc row-major, B = Wo^T so A@B^T = Wc@Wo)
  gemm_db<0><<<dim3(E / 128, E / 128), 256, 0, stream>>>(
      wcb, wotb, nullptr, wcombb, E, E, E, nullptr, nullptr, nullptr);

  gemm_db<2><<<dim3(M / 128, N3 / 128), 256, 0, stream>>>(
      xb, wqb, b_in, nullptr, M, N3, E, Qs, Kc, Vt);
  attn_fwd<<<dim3(8, 128), 256, 0, stream>>>(Qs, Kc, Vt, AO);
  // final = AO @ Wcomb^T + b2  (replaces out_proj AND c_proj)
  gemm_db<1><<<dim3(M / 128, E / 128), 256, 0, stream>>>(
      AO, wcombb, b2, out, M, E, E, nullptr, nullptr, nullptr);
}